// Round 5
// baseline (1884.566 us; speedup 1.0000x reference)
//
#include <hip/hip_runtime.h>

// ============================================================================
// Dilated GRU encoder-decoder, persistent-kernel design for MI355X. Round 10
// (= r7 source, fourth submission; r7-r9 never ran — GPU broker at capacity.
//  One defensive change: bounded spin in wait_group, see below.)
//
// r5 (4853.5 us, verified) = ~16 us/step; per-step compute ~0.5 us, so the
// handoff dominates. Diagnosis: the agent-scope FENCES, not the atomics.
// acquire-agent lowers to buffer_inv sc1 and release-agent to buffer_wbl2 sc1
// -- cache-WIDE L2 maintenance. 32 blocks/XCD x 2 fences x 304 steps of
// serialized cache-wide ops ~= the 16 us/step, and each invalidate also
// evicts the staged X tiles (refetched from L3 every step).
//
// This round: zero fences, placement-agnostic MALL-coherent exchange.
//   - h stores / flag stores: explicit `sc0 sc1` write-through stores (reach
//     the MALL coherence point; no dirty L2 line => no wbl2 needed).
//   - writer orders h-before-flag with s_waitcnt vmcnt(0) + __syncthreads.
//   - readers poll flags and load h with `sc0 sc1` loads (bypass stale
//     L1/L2), vectorized dwordx4, waitcnt inside the asm + sched_barrier(0)
//     (rule-18: MFMA can hoist past an asm waitcnt otherwise).
//   - groups remain blockIdx-based (complete by construction, no dispatch
//     assumptions). Correct for ANY block->XCD placement.
//   - DEFENSIVE: wait_group gives up after ~1M poll iterations (~25 ms;
//     legit waits are <= a few us). Never taken when the protocol is sound;
//     converts any hidden deadlock into a visible correctness failure
//     instead of an opaque harness hang.
// Compute, layouts, staging, reduction: byte-identical to r5 (absmax 3.9e-3
// proven there).
// ============================================================================

typedef __bf16 bf16x8 __attribute__((ext_vector_type(8)));
typedef float  f32x4  __attribute__((ext_vector_type(4)));
typedef unsigned int u32x4 __attribute__((ext_vector_type(4)));

#define MFMA16(a, b, c) __builtin_amdgcn_mfma_f32_16x16x32_bf16(a, b, c, 0, 0, 0)

// ---- workspace byte offsets (unchanged from r5) ----------------------------
#define OFF_FLG   0ULL          // 8 groups * 32 members * 64 B = 16384
#define OFF_HB    16384ULL      // 2 * 128 * 512 * 4 B (packed u32, dbuf)
#define OFF_XX0H  540672ULL     // 256*128*1024 bf16 = 67108864 B
#define OFF_XX0L  67649536ULL
#define OFF_XX1H  134758400ULL  // 48*128*512 bf16 = 6291456 B
#define OFF_XX1L  141049856ULL
#define NEED_FULL 147341312ULL  // staged path requires this many ws bytes

static __device__ __forceinline__ void split_bf(float x, unsigned short& hi,
                                                unsigned short& lo) {
  union { __bf16 b; unsigned short u; } c;
  c.b = (__bf16)x; hi = c.u;
  float fh = (float)c.b;
  c.b = (__bf16)(x - fh); lo = c.u;
}
static __device__ __forceinline__ void split8(const float* __restrict__ p,
                                              bf16x8& h, bf16x8& l) {
#pragma unroll
  for (int j = 0; j < 8; ++j) {
    const float x = p[j];
    const __bf16 hb = (__bf16)x;
    h[j] = hb;
    l[j] = (__bf16)(x - (float)hb);
  }
}
static __device__ __forceinline__ void split8a(const float* xv, bf16x8& h, bf16x8& l) {
#pragma unroll
  for (int j = 0; j < 8; ++j) {
    const float x = xv[j];
    const __bf16 hb = (__bf16)x;
    h[j] = hb;
    l[j] = (__bf16)(x - (float)hb);
  }
}
static __device__ __forceinline__ float sigmoidf_(float x) {
  return 1.0f / (1.0f + __expf(-x));
}
static __device__ __forceinline__ float tanhf_(float x) {
  x = fminf(fmaxf(x, -15.0f), 15.0f);
  float e = __expf(2.0f * x);
  return (e - 1.0f) / (e + 1.0f);
}

// ---- MALL-coherent (device-scope) primitives. sc0 sc1 = bypass L1 and L2;
// the op is served at the MALL, the true coherence point across XCDs. -------
static __device__ __forceinline__ void store_u32_mall(unsigned int* p,
                                                      unsigned int v) {
  asm volatile("global_store_dword %0, %1, off sc0 sc1"
               :: "v"(p), "v"(v) : "memory");
}
static __device__ __forceinline__ unsigned int load_u32_mall(const unsigned int* p) {
  unsigned int v;
  asm volatile("global_load_dword %0, %1, off sc0 sc1\n\t"
               "s_waitcnt vmcnt(0)"
               : "=v"(v) : "v"(p) : "memory");
  return v;
}
// 8x dwordx4 loads of one wave's h slice (byte offsets kt*128 + {0,16}),
// single waitcnt at the end. Early-clobber outputs keep dests off the addr.
static __device__ __forceinline__ void load_h8_mall(const unsigned int* base,
                                                    u32x4 hv[4][2]) {
  asm volatile(
      "global_load_dwordx4 %0, %8, off sc0 sc1\n\t"
      "global_load_dwordx4 %1, %8, off offset:16 sc0 sc1\n\t"
      "global_load_dwordx4 %2, %8, off offset:128 sc0 sc1\n\t"
      "global_load_dwordx4 %3, %8, off offset:144 sc0 sc1\n\t"
      "global_load_dwordx4 %4, %8, off offset:256 sc0 sc1\n\t"
      "global_load_dwordx4 %5, %8, off offset:272 sc0 sc1\n\t"
      "global_load_dwordx4 %6, %8, off offset:384 sc0 sc1\n\t"
      "global_load_dwordx4 %7, %8, off offset:400 sc0 sc1\n\t"
      "s_waitcnt vmcnt(0)"
      : "=&v"(hv[0][0]), "=&v"(hv[0][1]), "=&v"(hv[1][0]), "=&v"(hv[1][1]),
        "=&v"(hv[2][0]), "=&v"(hv[2][1]), "=&v"(hv[3][0]), "=&v"(hv[3][1])
      : "v"(base)
      : "memory");
}

// Wave 0 polls the 32 member flags (lane i -> member i's own 64B line) with
// MALL loads + s_sleep backoff; all waves rendezvous at the barrier. No
// fence: the writer drained its MALL-coherent h stores before its flag
// store, so flag-at-MALL implies h-at-MALL, and readers bypass L1/L2.
// Bounded: gives up after ~1M polls (~25 ms) -- never taken when sound;
// turns a protocol bug into a visible wrong-answer instead of a hang.
static __device__ __forceinline__ void wait_group(const unsigned int* __restrict__ flg,
                                                  int wave, int lane, unsigned int tgt) {
  if (wave == 0) {
    const unsigned int* fp = flg + (size_t)lane * 16;
    for (unsigned int it = 0; it < (1u << 20); ++it) {
      unsigned int v = tgt;
      if (lane < 32) v = load_u32_mall(fp);
      if (__all((int)(v >= tgt))) break;
      __builtin_amdgcn_s_sleep(1);
    }
  }
  __syncthreads();
}

// Publish: every thread's h store (sc0 sc1, write-through) is drained by its
// own vmcnt(0) before the barrier; tid0's flag store is issued strictly after.
static __device__ __forceinline__ void publish_group(unsigned int* myfl, int tid,
                                                     unsigned int val) {
  asm volatile("s_waitcnt vmcnt(0)" ::: "memory");
  __syncthreads();
  if (tid == 0) store_u32_mall(myfl, val);
}

// ---------------------------------------------------------------------------
// X0 (64,1024,512) fp32 -> XX0[t][n][c] hi/lo bf16, n = d*64+b, tau = 2t+d.
// ---------------------------------------------------------------------------
__global__ void prep_x0(const float* __restrict__ X0, unsigned short* __restrict__ XH) {
  unsigned short* XL = XH + 33554432;
  __shared__ float tile[32][65];
  const int b  = blockIdx.x;        // 0..63
  const int c0 = blockIdx.y * 32;   // 0..1023 step 32
  const int tid = threadIdx.x;      // 256
  for (int tb = 0; tb < 8; ++tb) {
    const int tau0 = tb * 64;
#pragma unroll
    for (int i = 0; i < 8; ++i) {
      const int cc  = (tid >> 6) + 4 * i;
      const int tau = tid & 63;
      tile[cc][tau] = X0[(size_t)b * 524288 + (size_t)(c0 + cc) * 512 + tau0 + tau];
    }
    __syncthreads();
#pragma unroll
    for (int s = 0; s < 8; ++s) {
      const int cc  = tid & 31;
      const int tau = (tid >> 5) * 8 + s;
      const int gt  = tau0 + tau;
      const int tt  = gt >> 1, d = gt & 1;
      unsigned short h, l;
      split_bf(tile[cc][tau], h, l);
      const size_t o = (size_t)tt * 131072 + (size_t)(d * 64 + b) * 1024 + c0 + cc;
      XH[o] = h; XL[o] = l;
    }
    __syncthreads();
  }
}

// ---------------------------------------------------------------------------
// X1 (64,512,96) fp32 -> XX1[t][n][h] hi/lo bf16, t<48, tau = 2t+d.
// ---------------------------------------------------------------------------
__global__ void prep_x1(const float* __restrict__ X1, unsigned short* __restrict__ XH) {
  unsigned short* XL = XH + 3145728;
  __shared__ float tile[32][97];
  const int b  = blockIdx.x;        // 0..63
  const int h0 = blockIdx.y * 32;   // 0..511 step 32
  const int tid = threadIdx.x;
#pragma unroll
  for (int i = 0; i < 12; ++i) {
    const int idx = i * 256 + tid;  // < 3072
    const int cc = idx / 96, tau = idx % 96;
    tile[cc][tau] = X1[(size_t)b * 49152 + (size_t)(h0 + cc) * 96 + tau];
  }
  __syncthreads();
#pragma unroll
  for (int i = 0; i < 12; ++i) {
    const int idx = i * 256 + tid;
    const int cc = idx & 31, tau = idx >> 5;  // tau 0..95
    const int tt = tau >> 1, d = tau & 1;
    unsigned short h, l;
    split_bf(tile[cc][tau], h, l);
    const size_t o = (size_t)tt * 65536 + (size_t)(d * 64 + b) * 512 + h0 + cc;
    XH[o] = h; XL[o] = l;
  }
}

// ---------------------------------------------------------------------------
// Persistent recurrent kernel. Grid = 256 blocks x 256 threads (1 WG/CU).
// ---------------------------------------------------------------------------
template <bool STAGED>
__launch_bounds__(256, 1)
__global__ void rnn_persistent(unsigned char* __restrict__ ws,
                               const float* __restrict__ X0, const float* __restrict__ X1,
                               const float* __restrict__ WihE, const float* __restrict__ WhhE,
                               const float* __restrict__ bihE, const float* __restrict__ bhhE,
                               const float* __restrict__ WihD, const float* __restrict__ WhhD,
                               const float* __restrict__ bihD, const float* __restrict__ bhhD,
                               float* __restrict__ out) {
  const int tid  = threadIdx.x;
  const int wave = tid >> 6;
  const int lane = tid & 63;
  const int l15  = lane & 15;
  const int quad = lane >> 4;

  const int g  = blockIdx.x & 7;   // group (complete by construction)
  const int m  = blockIdx.x >> 3;  // member 0..31
  const int rb = g * 16;           // batch-row base of group
  const int ib = m * 16;           // hidden-i base of this member

  const unsigned short* XX0H = (const unsigned short*)(ws + OFF_XX0H);
  const unsigned short* XX0L = (const unsigned short*)(ws + OFF_XX0L);
  const unsigned short* XX1H = (const unsigned short*)(ws + OFF_XX1H);
  const unsigned short* XX1L = (const unsigned short*)(ws + OFF_XX1L);
  unsigned int* HbP  = (unsigned int*)(ws + OFF_HB);   // [2][128][512] packed
  unsigned int* flg  = (unsigned int*)(ws + OFF_FLG) + (size_t)g * 512;  // 32*16 u32
  unsigned int* myfl = flg + (size_t)m * 16;

  __shared__ float red[4][6][256];  // 24 KB

  const int r_row = tid >> 4;   // batch row within group (gate phase)
  const int ii    = tid & 15;
  const int ig    = ib + ii;

  const int an    = rb + l15;               // A-operand batch row
  const int ab    = an & 63, ad = an >> 6;  // original batch / dilation
  const int onrow = rb + r_row;
  const int ob    = onrow & 63, od = onrow >> 6;

  const float bieR = bihE[ig], bieZ = bihE[512 + ig], bieN = bihE[1024 + ig];
  const float bheR = bhhE[ig], bheZ = bhhE[512 + ig], bheN = bhhE[1024 + ig];
  const float bidR = bihD[ig], bidZ = bihD[512 + ig], bidN = bihD[1024 + ig];
  const float bhdR = bhhD[ig], bhdZ = bhhD[512 + ig], bhdN = bhhD[1024 + ig];

  // ---- encoder weight fragments: fp32 -> hi/lo split in registers.
  bf16x8 WIH_H[24], WIH_L[24], WHH_H[12], WHH_L[12];
#pragma unroll
  for (int kt = 0; kt < 8; ++kt)
#pragma unroll
    for (int nt = 0; nt < 3; ++nt)
      split8(WihE + (size_t)(nt * 512 + ib + l15) * 1024 + (wave * 8 + kt) * 32 + quad * 8,
             WIH_H[kt * 3 + nt], WIH_L[kt * 3 + nt]);
#pragma unroll
  for (int kt = 0; kt < 4; ++kt)
#pragma unroll
    for (int nt = 0; nt < 3; ++nt)
      split8(WhhE + (size_t)(nt * 512 + ib + l15) * 512 + (wave * 4 + kt) * 32 + quad * 8,
             WHH_H[kt * 3 + nt], WHH_L[kt * 3 + nt]);

  // ---- init h(0) = 0 into parity-0 buffer, publish (flag value = 1)
  float h_reg = 0.0f;
  store_u32_mall(HbP + (size_t)onrow * 512 + ig, 0u);
  publish_group(myfl, tid, 1u);

  // ===================== encoder: 256 steps =====================
  for (int t = 0; t < 256; ++t) {
    const int par  = t & 1;
    const int wpar = (t + 1) & 1;

    // ---- gi = x[t] @ WihE^T  (independent of h; before the wait)
    f32x4 gi0 = {0,0,0,0}, gi1 = {0,0,0,0}, gi2 = {0,0,0,0};
    const size_t xb  = ((size_t)t * 128 + an) * 1024 + quad * 8;  // staged
    const int    tau = 2 * t + ad;                                 // direct
#pragma unroll
    for (int kt = 0; kt < 8; ++kt) {
      bf16x8 axh, axl;
      if constexpr (STAGED) {
        axh = *reinterpret_cast<const bf16x8*>(XX0H + xb + (wave * 8 + kt) * 32);
        axl = *reinterpret_cast<const bf16x8*>(XX0L + xb + (wave * 8 + kt) * 32);
      } else {
        float xv[8];
#pragma unroll
        for (int j = 0; j < 8; ++j)
          xv[j] = X0[(size_t)ab * 524288 +
                     (size_t)((wave * 8 + kt) * 32 + quad * 8 + j) * 512 + tau];
        split8a(xv, axh, axl);
      }
      gi0 = MFMA16(axh, WIH_H[kt * 3 + 0], gi0);
      gi1 = MFMA16(axh, WIH_H[kt * 3 + 1], gi1);
      gi2 = MFMA16(axh, WIH_H[kt * 3 + 2], gi2);
      gi0 = MFMA16(axl, WIH_H[kt * 3 + 0], gi0);
      gi1 = MFMA16(axl, WIH_H[kt * 3 + 1], gi1);
      gi2 = MFMA16(axl, WIH_H[kt * 3 + 2], gi2);
      gi0 = MFMA16(axh, WIH_L[kt * 3 + 0], gi0);
      gi1 = MFMA16(axh, WIH_L[kt * 3 + 1], gi1);
      gi2 = MFMA16(axh, WIH_L[kt * 3 + 2], gi2);
    }

    // ---- wait for h(t) from all group members
    wait_group(flg, wave, lane, (unsigned int)(t + 1));

    // ---- vectorized MALL h loads (bypass stale L1/L2)
    const unsigned int* hrow = HbP + (size_t)par * 65536 + (size_t)an * 512 + quad * 8;
    u32x4 hv[4][2];
    load_h8_mall(hrow + (size_t)wave * 128, hv);
    __builtin_amdgcn_sched_barrier(0);

    f32x4 gh0 = {0,0,0,0}, gh1 = {0,0,0,0}, gh2 = {0,0,0,0};
#pragma unroll
    for (int kt = 0; kt < 4; ++kt) {
      bf16x8 ahh, ahl;
      union { unsigned short u; __bf16 b; } c;
#pragma unroll
      for (int j = 0; j < 8; ++j) {
        const unsigned int w = hv[kt][j >> 2][j & 3];
        c.u = (unsigned short)(w & 0xffffu); ahh[j] = c.b;
        c.u = (unsigned short)(w >> 16);     ahl[j] = c.b;
      }
      gh0 = MFMA16(ahh, WHH_H[kt * 3 + 0], gh0);
      gh1 = MFMA16(ahh, WHH_H[kt * 3 + 1], gh1);
      gh2 = MFMA16(ahh, WHH_H[kt * 3 + 2], gh2);
      gh0 = MFMA16(ahl, WHH_H[kt * 3 + 0], gh0);
      gh1 = MFMA16(ahl, WHH_H[kt * 3 + 1], gh1);
      gh2 = MFMA16(ahl, WHH_H[kt * 3 + 2], gh2);
      gh0 = MFMA16(ahh, WHH_L[kt * 3 + 0], gh0);
      gh1 = MFMA16(ahh, WHH_L[kt * 3 + 1], gh1);
      gh2 = MFMA16(ahh, WHH_L[kt * 3 + 2], gh2);
    }

    // ---- reduce 4 wave-partials (C/D layout: row=quad*4+q, col=l15)
#pragma unroll
    for (int q = 0; q < 4; ++q) {
      const int base = (quad * 4 + q) * 16 + l15;
      red[wave][0][base] = gi0[q]; red[wave][1][base] = gi1[q]; red[wave][2][base] = gi2[q];
      red[wave][3][base] = gh0[q]; red[wave][4][base] = gh1[q]; red[wave][5][base] = gh2[q];
    }
    __syncthreads();
    float sR = 0, sZ = 0, sN = 0, hR = 0, hZ = 0, hN = 0;
#pragma unroll
    for (int w = 0; w < 4; ++w) {
      sR += red[w][0][tid]; sZ += red[w][1][tid]; sN += red[w][2][tid];
      hR += red[w][3][tid]; hZ += red[w][4][tid]; hN += red[w][5][tid];
    }
    const float rr = sigmoidf_(sR + bieR + hR + bheR);
    const float zz = sigmoidf_(sZ + bieZ + hZ + bheZ);
    const float nn = tanhf_(sN + bieN + rr * (hN + bheN));
    h_reg = (1.0f - zz) * nn + zz * h_reg;
    unsigned short ph, pl;
    split_bf(h_reg, ph, pl);
    store_u32_mall(HbP + (size_t)wpar * 65536 + (size_t)onrow * 512 + ig,
                   (unsigned int)ph | ((unsigned int)pl << 16));
    publish_group(myfl, tid, (unsigned int)(t + 2));
  }

  // ===================== decoder weights (fp32 -> split, reuse regs) ========
  bf16x8 D1H[12], D1L[12], D2H[12], D2L[12], DHH[12], DHL[12];
#pragma unroll
  for (int kt = 0; kt < 4; ++kt)
#pragma unroll
    for (int nt = 0; nt < 3; ++nt) {
      const size_t row = (size_t)(nt * 512 + ib + l15);
      const int    k   = (wave * 4 + kt) * 32 + quad * 8;
      split8(WihD + row * 1024 + k,       D1H[kt * 3 + nt], D1L[kt * 3 + nt]);
      split8(WihD + row * 1024 + 512 + k, D2H[kt * 3 + nt], D2L[kt * 3 + nt]);
      split8(WhhD + row * 512 + k,        DHH[kt * 3 + nt], DHL[kt * 3 + nt]);
    }

  float* orow = out + (size_t)ob * 49152 + (size_t)ig * 96 + od;

  // ===================== decoder: 48 steps (global step gt = 256 + t) =======
  for (int t = 0; t < 48; ++t) {
    const int gt   = 256 + t;
    const int par  = gt & 1;
    const int wpar = (gt + 1) & 1;

    // ---- x1 part of gi (independent of h)
    f32x4 gi0 = {0,0,0,0}, gi1 = {0,0,0,0}, gi2 = {0,0,0,0};
    const size_t x1b = ((size_t)t * 128 + an) * 512 + quad * 8;  // staged
    const int    tau = 2 * t + ad;                                // direct
#pragma unroll
    for (int kt = 0; kt < 4; ++kt) {
      bf16x8 axh, axl;
      if constexpr (STAGED) {
        axh = *reinterpret_cast<const bf16x8*>(XX1H + x1b + (wave * 4 + kt) * 32);
        axl = *reinterpret_cast<const bf16x8*>(XX1L + x1b + (wave * 4 + kt) * 32);
      } else {
        float xv[8];
#pragma unroll
        for (int j = 0; j < 8; ++j)
          xv[j] = X1[(size_t)ab * 49152 +
                     (size_t)((wave * 4 + kt) * 32 + quad * 8 + j) * 96 + tau];
        split8a(xv, axh, axl);
      }
      gi0 = MFMA16(axh, D2H[kt * 3 + 0], gi0);
      gi1 = MFMA16(axh, D2H[kt * 3 + 1], gi1);
      gi2 = MFMA16(axh, D2H[kt * 3 + 2], gi2);
      gi0 = MFMA16(axl, D2H[kt * 3 + 0], gi0);
      gi1 = MFMA16(axl, D2H[kt * 3 + 1], gi1);
      gi2 = MFMA16(axl, D2H[kt * 3 + 2], gi2);
      gi0 = MFMA16(axh, D2L[kt * 3 + 0], gi0);
      gi1 = MFMA16(axh, D2L[kt * 3 + 1], gi1);
      gi2 = MFMA16(axh, D2L[kt * 3 + 2], gi2);
    }

    wait_group(flg, wave, lane, (unsigned int)(gt + 1));

    // ---- h parts: gi += h@Wd1^T (din == h), gh = h@WhhD^T
    const unsigned int* hrow = HbP + (size_t)par * 65536 + (size_t)an * 512 + quad * 8;
    u32x4 hv[4][2];
    load_h8_mall(hrow + (size_t)wave * 128, hv);
    __builtin_amdgcn_sched_barrier(0);

    f32x4 gh0 = {0,0,0,0}, gh1 = {0,0,0,0}, gh2 = {0,0,0,0};
#pragma unroll
    for (int kt = 0; kt < 4; ++kt) {
      bf16x8 ahh, ahl;
      union { unsigned short u; __bf16 b; } c;
#pragma unroll
      for (int j = 0; j < 8; ++j) {
        const unsigned int w = hv[kt][j >> 2][j & 3];
        c.u = (unsigned short)(w & 0xffffu); ahh[j] = c.b;
        c.u = (unsigned short)(w >> 16);     ahl[j] = c.b;
      }
      gi0 = MFMA16(ahh, D1H[kt * 3 + 0], gi0);
      gi1 = MFMA16(ahh, D1H[kt * 3 + 1], gi1);
      gi2 = MFMA16(ahh, D1H[kt * 3 + 2], gi2);
      gi0 = MFMA16(ahl, D1H[kt * 3 + 0], gi0);
      gi1 = MFMA16(ahl, D1H[kt * 3 + 1], gi1);
      gi2 = MFMA16(ahl, D1H[kt * 3 + 2], gi2);
      gi0 = MFMA16(ahh, D1L[kt * 3 + 0], gi0);
      gi1 = MFMA16(ahh, D1L[kt * 3 + 1], gi1);
      gi2 = MFMA16(ahh, D1L[kt * 3 + 2], gi2);
      gh0 = MFMA16(ahh, DHH[kt * 3 + 0], gh0);
      gh1 = MFMA16(ahh, DHH[kt * 3 + 1], gh1);
      gh2 = MFMA16(ahh, DHH[kt * 3 + 2], gh2);
      gh0 = MFMA16(ahl, DHH[kt * 3 + 0], gh0);
      gh1 = MFMA16(ahl, DHH[kt * 3 + 1], gh1);
      gh2 = MFMA16(ahl, DHH[kt * 3 + 2], gh2);
      gh0 = MFMA16(ahh, DHL[kt * 3 + 0], gh0);
      gh1 = MFMA16(ahh, DHL[kt * 3 + 1], gh1);
      gh2 = MFMA16(ahh, DHL[kt * 3 + 2], gh2);
    }

#pragma unroll
    for (int q = 0; q < 4; ++q) {
      const int base = (quad * 4 + q) * 16 + l15;
      red[wave][0][base] = gi0[q]; red[wave][1][base] = gi1[q]; red[wave][2][base] = gi2[q];
      red[wave][3][base] = gh0[q]; red[wave][4][base] = gh1[q]; red[wave][5][base] = gh2[q];
    }
    __syncthreads();
    float sR = 0, sZ = 0, sN = 0, hR = 0, hZ = 0, hN = 0;
#pragma unroll
    for (int w = 0; w < 4; ++w) {
      sR += red[w][0][tid]; sZ += red[w][1][tid]; sN += red[w][2][tid];
      hR += red[w][3][tid]; hZ += red[w][4][tid]; hN += red[w][5][tid];
    }
    const float rr = sigmoidf_(sR + bidR + hR + bhdR);
    const float zz = sigmoidf_(sZ + bidZ + hZ + bhdZ);
    const float nn = tanhf_(sN + bidN + rr * (hN + bhdN));
    h_reg = (1.0f - zz) * nn + zz * h_reg;
    unsigned short ph, pl;
    split_bf(h_reg, ph, pl);
    store_u32_mall(HbP + (size_t)wpar * 65536 + (size_t)onrow * 512 + ig,
                   (unsigned int)ph | ((unsigned int)pl << 16));
    orow[2 * t] = h_reg;  // o[b][ig][2t+d]
    if (t < 47) {
      publish_group(myfl, tid, (unsigned int)(gt + 2));
    }
  }
}

extern "C" void kernel_launch(void* const* d_in, const int* in_sizes, int n_in,
                              void* d_out, int out_size, void* d_ws, size_t ws_size,
                              hipStream_t stream) {
  (void)in_sizes; (void)n_in; (void)out_size;
  const float* X0   = (const float*)d_in[0];
  const float* X1   = (const float*)d_in[1];
  // d_in[2] = seqlen (unused, fixed 512)
  const float* WihE = (const float*)d_in[3];
  const float* WhhE = (const float*)d_in[4];
  const float* bihE = (const float*)d_in[5];
  const float* bhhE = (const float*)d_in[6];
  const float* WihD = (const float*)d_in[7];
  const float* WhhD = (const float*)d_in[8];
  const float* bihD = (const float*)d_in[9];
  const float* bhhD = (const float*)d_in[10];
  unsigned char* ws = (unsigned char*)d_ws;

  const bool staged = (ws_size >= NEED_FULL);  // ws_size constant -> graph-safe

  hipMemsetAsync(ws + OFF_FLG, 0, 16384, stream);
  if (staged) {
    prep_x0<<<dim3(64, 32), 256, 0, stream>>>(X0, (unsigned short*)(ws + OFF_XX0H));
    prep_x1<<<dim3(64, 16), 256, 0, stream>>>(X1, (unsigned short*)(ws + OFF_XX1H));
    rnn_persistent<true><<<256, 256, 0, stream>>>(ws, X0, X1, WihE, WhhE, bihE, bhhE,
                                                  WihD, WhhD, bihD, bhhD, (float*)d_out);
  } else {
    rnn_persistent<false><<<256, 256, 0, stream>>>(ws, X0, X1, WihE, WhhE, bihE, bhhE,
                                                   WihD, WhhD, bihD, bhhD, (float*)d_out);
  }
}

// Round 13
// 1696.935 us; speedup vs baseline: 1.1106x; 1.1106x over previous
//
#include <hip/hip_runtime.h>

// ============================================================================
// Dilated GRU encoder-decoder, persistent-kernel design for MI355X. Round 18
// (= r11 source, eighth submission; r11-r17 never ran — GPU broker at
//  capacity. Byte-identical resubmission for clean attribution vs r10.)
//
// r10 (1884.6 us total, kernel ~1699 us, PASSED, absmax 3.9e-3): fence-free
// MALL protocol gave 2.58x over r5. Counters: MfmaUtil 13.5%, HBM 2.2%,
// 5.6 us/step -> still handoff-latency-bound. Residual cost = ~3 serialized
// MALL round trips/step: publish vmcnt-drain, flag-poll detection (+s_sleep
// quantum), then the h-load drain after the barrier.
//
// This round: ZERO-FLAG protocol — self-validating stamped h-data.
//   - Steal bit16 of each packed h dword (LSB of the lo-bf16 correction;
//     numeric impact ~2^-16 * |h|, far below tolerance) as a step stamp
//     = ((m+1)>>1)&1 for h(m) in the 2-slot ring (slot m&1).
//   - Readers: per-wave retry of the 8x dwordx4 sc0/sc1 h loads until all
//     32 stamps match. The data load IS the sync — no flags, no poll round
//     trip, no publish drain, no block-wide wait barrier.
//   - Writers: fire-and-forget stamped sc0/sc1 stores after the gates.
//   - Safety (audited r12-r18): while any member still reads h(t), no h(t+1)
//     or later can have been written (dependency chain), so slot t&1 holds
//     only h(t-2) (stamp mismatch -> retry) or h(t) (match). Writes of
//     h(t+1) target the opposite slot -> no WAR. Same-thread WAW to a slot
//     is ordered by the loop-tail __syncthreads (compiler emits vmcnt(0)
//     drain before s_barrier). Stamps alternate per slot. Read-own-write is
//     benign (MALL or store-queue both return the fresh stamped value).
//     asm volatile + "memory" in a data-dependent loop -> no hoist/CSE.
//   - h(0)=0 pre-validated by hipMemsetAsync of the ring (stamp 0 = valid).
//   - Bounded retry (~1M iters) keeps any protocol bug a visible wrong
//     answer instead of a hang (and a failed run still yields dur_us+PMC,
//     which tests the latency model regardless).
//   - LDS-reduce bank conflicts (1.5e7 cy) left untouched for attribution.
// Compute, layouts, staging, reduction: byte-identical to r10.
// ============================================================================

typedef __bf16 bf16x8 __attribute__((ext_vector_type(8)));
typedef float  f32x4  __attribute__((ext_vector_type(4)));
typedef unsigned int u32x4 __attribute__((ext_vector_type(4)));

#define MFMA16(a, b, c) __builtin_amdgcn_mfma_f32_16x16x32_bf16(a, b, c, 0, 0, 0)

// ---- workspace byte offsets (unchanged layout; FLG region now unused) ------
#define OFF_FLG   0ULL          // (unused in r18)
#define OFF_HB    16384ULL      // 2 * 128 * 512 * 4 B (packed u32, 2-slot ring)
#define OFF_XX0H  540672ULL     // 256*128*1024 bf16 = 67108864 B
#define OFF_XX0L  67649536ULL
#define OFF_XX1H  134758400ULL  // 48*128*512 bf16 = 6291456 B
#define OFF_XX1L  141049856ULL
#define NEED_FULL 147341312ULL  // staged path requires this many ws bytes

static __device__ __forceinline__ void split_bf(float x, unsigned short& hi,
                                                unsigned short& lo) {
  union { __bf16 b; unsigned short u; } c;
  c.b = (__bf16)x; hi = c.u;
  float fh = (float)c.b;
  c.b = (__bf16)(x - fh); lo = c.u;
}
static __device__ __forceinline__ void split8(const float* __restrict__ p,
                                              bf16x8& h, bf16x8& l) {
#pragma unroll
  for (int j = 0; j < 8; ++j) {
    const float x = p[j];
    const __bf16 hb = (__bf16)x;
    h[j] = hb;
    l[j] = (__bf16)(x - (float)hb);
  }
}
static __device__ __forceinline__ void split8a(const float* xv, bf16x8& h, bf16x8& l) {
#pragma unroll
  for (int j = 0; j < 8; ++j) {
    const float x = xv[j];
    const __bf16 hb = (__bf16)x;
    h[j] = hb;
    l[j] = (__bf16)(x - (float)hb);
  }
}
static __device__ __forceinline__ float sigmoidf_(float x) {
  return 1.0f / (1.0f + __expf(-x));
}
static __device__ __forceinline__ float tanhf_(float x) {
  x = fminf(fmaxf(x, -15.0f), 15.0f);
  float e = __expf(2.0f * x);
  return (e - 1.0f) / (e + 1.0f);
}

// ---- MALL-coherent primitives. sc0 sc1 = bypass L1 and L2; served at the
// MALL, the true coherence point across XCDs (visibility proven by r10). ----
static __device__ __forceinline__ void store_u32_mall(unsigned int* p,
                                                      unsigned int v) {
  asm volatile("global_store_dword %0, %1, off sc0 sc1"
               :: "v"(p), "v"(v) : "memory");
}
// 8x dwordx4 loads of one wave's h slice (byte offsets kt*128 + {0,16}),
// single waitcnt at the end. Early-clobber outputs keep dests off the addr.
static __device__ __forceinline__ void load_h8_mall(const unsigned int* base,
                                                    u32x4 hv[4][2]) {
  asm volatile(
      "global_load_dwordx4 %0, %8, off sc0 sc1\n\t"
      "global_load_dwordx4 %1, %8, off offset:16 sc0 sc1\n\t"
      "global_load_dwordx4 %2, %8, off offset:128 sc0 sc1\n\t"
      "global_load_dwordx4 %3, %8, off offset:144 sc0 sc1\n\t"
      "global_load_dwordx4 %4, %8, off offset:256 sc0 sc1\n\t"
      "global_load_dwordx4 %5, %8, off offset:272 sc0 sc1\n\t"
      "global_load_dwordx4 %6, %8, off offset:384 sc0 sc1\n\t"
      "global_load_dwordx4 %7, %8, off offset:400 sc0 sc1\n\t"
      "s_waitcnt vmcnt(0)"
      : "=&v"(hv[0][0]), "=&v"(hv[0][1]), "=&v"(hv[1][0]), "=&v"(hv[1][1]),
        "=&v"(hv[2][0]), "=&v"(hv[2][1]), "=&v"(hv[3][0]), "=&v"(hv[3][1])
      : "v"(base)
      : "memory");
}

// Per-wave stamped retry: reload the wave's h slice until every dword's
// stamp (bit16) matches. Bounded (~1M iters) so a protocol bug surfaces as a
// wrong answer, not a hang. sched_barrier(0) after the final load blocks the
// rule-18 MFMA-hoist hazard at the call site.
static __device__ __forceinline__ void load_h8_stamped(const unsigned int* base,
                                                       u32x4 hv[4][2],
                                                       unsigned int stamp) {
  for (unsigned int it = 0; it < (1u << 20); ++it) {
    load_h8_mall(base, hv);
    unsigned int d = 0;
#pragma unroll
    for (int kt = 0; kt < 4; ++kt)
#pragma unroll
      for (int p = 0; p < 2; ++p)
#pragma unroll
        for (int j = 0; j < 4; ++j)
          d |= ((hv[kt][p][j] >> 16) ^ stamp) & 1u;
    if (__all((int)(d == 0))) break;
  }
  __builtin_amdgcn_sched_barrier(0);
}

// ---------------------------------------------------------------------------
// X0 (64,1024,512) fp32 -> XX0[t][n][c] hi/lo bf16, n = d*64+b, tau = 2t+d.
// ---------------------------------------------------------------------------
__global__ void prep_x0(const float* __restrict__ X0, unsigned short* __restrict__ XH) {
  unsigned short* XL = XH + 33554432;
  __shared__ float tile[32][65];
  const int b  = blockIdx.x;        // 0..63
  const int c0 = blockIdx.y * 32;   // 0..1023 step 32
  const int tid = threadIdx.x;      // 256
  for (int tb = 0; tb < 8; ++tb) {
    const int tau0 = tb * 64;
#pragma unroll
    for (int i = 0; i < 8; ++i) {
      const int cc  = (tid >> 6) + 4 * i;
      const int tau = tid & 63;
      tile[cc][tau] = X0[(size_t)b * 524288 + (size_t)(c0 + cc) * 512 + tau0 + tau];
    }
    __syncthreads();
#pragma unroll
    for (int s = 0; s < 8; ++s) {
      const int cc  = tid & 31;
      const int tau = (tid >> 5) * 8 + s;
      const int gt  = tau0 + tau;
      const int tt  = gt >> 1, d = gt & 1;
      unsigned short h, l;
      split_bf(tile[cc][tau], h, l);
      const size_t o = (size_t)tt * 131072 + (size_t)(d * 64 + b) * 1024 + c0 + cc;
      XH[o] = h; XL[o] = l;
    }
    __syncthreads();
  }
}

// ---------------------------------------------------------------------------
// X1 (64,512,96) fp32 -> XX1[t][n][h] hi/lo bf16, t<48, tau = 2t+d.
// ---------------------------------------------------------------------------
__global__ void prep_x1(const float* __restrict__ X1, unsigned short* __restrict__ XH) {
  unsigned short* XL = XH + 3145728;
  __shared__ float tile[32][97];
  const int b  = blockIdx.x;        // 0..63
  const int h0 = blockIdx.y * 32;   // 0..511 step 32
  const int tid = threadIdx.x;
#pragma unroll
  for (int i = 0; i < 12; ++i) {
    const int idx = i * 256 + tid;  // < 3072
    const int cc = idx / 96, tau = idx % 96;
    tile[cc][tau] = X1[(size_t)b * 49152 + (size_t)(h0 + cc) * 96 + tau];
  }
  __syncthreads();
#pragma unroll
  for (int i = 0; i < 12; ++i) {
    const int idx = i * 256 + tid;
    const int cc = idx & 31, tau = idx >> 5;  // tau 0..95
    const int tt = tau >> 1, d = tau & 1;
    unsigned short h, l;
    split_bf(tile[cc][tau], h, l);
    const size_t o = (size_t)tt * 65536 + (size_t)(d * 64 + b) * 512 + h0 + cc;
    XH[o] = h; XL[o] = l;
  }
}

// ---------------------------------------------------------------------------
// Persistent recurrent kernel. Grid = 256 blocks x 256 threads (1 WG/CU).
// ---------------------------------------------------------------------------
template <bool STAGED>
__launch_bounds__(256, 1)
__global__ void rnn_persistent(unsigned char* __restrict__ ws,
                               const float* __restrict__ X0, const float* __restrict__ X1,
                               const float* __restrict__ WihE, const float* __restrict__ WhhE,
                               const float* __restrict__ bihE, const float* __restrict__ bhhE,
                               const float* __restrict__ WihD, const float* __restrict__ WhhD,
                               const float* __restrict__ bihD, const float* __restrict__ bhhD,
                               float* __restrict__ out) {
  const int tid  = threadIdx.x;
  const int wave = tid >> 6;
  const int lane = tid & 63;
  const int l15  = lane & 15;
  const int quad = lane >> 4;

  const int g  = blockIdx.x & 7;   // group (complete by construction)
  const int m  = blockIdx.x >> 3;  // member 0..31
  const int rb = g * 16;           // batch-row base of group
  const int ib = m * 16;           // hidden-i base of this member

  const unsigned short* XX0H = (const unsigned short*)(ws + OFF_XX0H);
  const unsigned short* XX0L = (const unsigned short*)(ws + OFF_XX0L);
  const unsigned short* XX1H = (const unsigned short*)(ws + OFF_XX1H);
  const unsigned short* XX1L = (const unsigned short*)(ws + OFF_XX1L);
  unsigned int* HbP  = (unsigned int*)(ws + OFF_HB);   // [2][128][512] packed ring

  __shared__ float red[4][6][256];  // 24 KB

  const int r_row = tid >> 4;   // batch row within group (gate phase)
  const int ii    = tid & 15;
  const int ig    = ib + ii;

  const int an    = rb + l15;               // A-operand batch row
  const int ab    = an & 63, ad = an >> 6;  // original batch / dilation
  const int onrow = rb + r_row;
  const int ob    = onrow & 63, od = onrow >> 6;

  const float bieR = bihE[ig], bieZ = bihE[512 + ig], bieN = bihE[1024 + ig];
  const float bheR = bhhE[ig], bheZ = bhhE[512 + ig], bheN = bhhE[1024 + ig];
  const float bidR = bihD[ig], bidZ = bihD[512 + ig], bidN = bihD[1024 + ig];
  const float bhdR = bhhD[ig], bhdZ = bhhD[512 + ig], bhdN = bhhD[1024 + ig];

  // ---- encoder weight fragments: fp32 -> hi/lo split in registers.
  bf16x8 WIH_H[24], WIH_L[24], WHH_H[12], WHH_L[12];
#pragma unroll
  for (int kt = 0; kt < 8; ++kt)
#pragma unroll
    for (int nt = 0; nt < 3; ++nt)
      split8(WihE + (size_t)(nt * 512 + ib + l15) * 1024 + (wave * 8 + kt) * 32 + quad * 8,
             WIH_H[kt * 3 + nt], WIH_L[kt * 3 + nt]);
#pragma unroll
  for (int kt = 0; kt < 4; ++kt)
#pragma unroll
    for (int nt = 0; nt < 3; ++nt)
      split8(WhhE + (size_t)(nt * 512 + ib + l15) * 512 + (wave * 4 + kt) * 32 + quad * 8,
             WHH_H[kt * 3 + nt], WHH_L[kt * 3 + nt]);

  // h(0) = 0 comes pre-validated from the host-side memset (stamp 0 = valid).
  float h_reg = 0.0f;

  // ===================== encoder: 256 steps =====================
  for (int t = 0; t < 256; ++t) {
    const int rslot = t & 1;
    const int wslot = (t + 1) & 1;
    const unsigned int rstamp = ((unsigned int)(t + 1) >> 1) & 1u;  // stamp of h(t)
    const unsigned int wstamp = ((unsigned int)(t + 2) >> 1) & 1u;  // stamp of h(t+1)

    // ---- gi = x[t] @ WihE^T  (independent of h; overlaps producer skew)
    f32x4 gi0 = {0,0,0,0}, gi1 = {0,0,0,0}, gi2 = {0,0,0,0};
    const size_t xb  = ((size_t)t * 128 + an) * 1024 + quad * 8;  // staged
    const int    tau = 2 * t + ad;                                 // direct
#pragma unroll
    for (int kt = 0; kt < 8; ++kt) {
      bf16x8 axh, axl;
      if constexpr (STAGED) {
        axh = *reinterpret_cast<const bf16x8*>(XX0H + xb + (wave * 8 + kt) * 32);
        axl = *reinterpret_cast<const bf16x8*>(XX0L + xb + (wave * 8 + kt) * 32);
      } else {
        float xv[8];
#pragma unroll
        for (int j = 0; j < 8; ++j)
          xv[j] = X0[(size_t)ab * 524288 +
                     (size_t)((wave * 8 + kt) * 32 + quad * 8 + j) * 512 + tau];
        split8a(xv, axh, axl);
      }
      gi0 = MFMA16(axh, WIH_H[kt * 3 + 0], gi0);
      gi1 = MFMA16(axh, WIH_H[kt * 3 + 1], gi1);
      gi2 = MFMA16(axh, WIH_H[kt * 3 + 2], gi2);
      gi0 = MFMA16(axl, WIH_H[kt * 3 + 0], gi0);
      gi1 = MFMA16(axl, WIH_H[kt * 3 + 1], gi1);
      gi2 = MFMA16(axl, WIH_H[kt * 3 + 2], gi2);
      gi0 = MFMA16(axh, WIH_L[kt * 3 + 0], gi0);
      gi1 = MFMA16(axh, WIH_L[kt * 3 + 1], gi1);
      gi2 = MFMA16(axh, WIH_L[kt * 3 + 2], gi2);
    }

    // ---- stamped h read: the load IS the sync (per-wave, 8 producers)
    const unsigned int* hrow = HbP + (size_t)rslot * 65536 + (size_t)an * 512 + quad * 8;
    u32x4 hv[4][2];
    load_h8_stamped(hrow + (size_t)wave * 128, hv, rstamp);

    f32x4 gh0 = {0,0,0,0}, gh1 = {0,0,0,0}, gh2 = {0,0,0,0};
#pragma unroll
    for (int kt = 0; kt < 4; ++kt) {
      bf16x8 ahh, ahl;
      union { unsigned short u; __bf16 b; } c;
#pragma unroll
      for (int j = 0; j < 8; ++j) {
        const unsigned int w = hv[kt][j >> 2][j & 3];
        c.u = (unsigned short)(w & 0xffffu); ahh[j] = c.b;
        c.u = (unsigned short)(w >> 16);     ahl[j] = c.b;  // stamp bit rides along (~2^-16)
      }
      gh0 = MFMA16(ahh, WHH_H[kt * 3 + 0], gh0);
      gh1 = MFMA16(ahh, WHH_H[kt * 3 + 1], gh1);
      gh2 = MFMA16(ahh, WHH_H[kt * 3 + 2], gh2);
      gh0 = MFMA16(ahl, WHH_H[kt * 3 + 0], gh0);
      gh1 = MFMA16(ahl, WHH_H[kt * 3 + 1], gh1);
      gh2 = MFMA16(ahl, WHH_H[kt * 3 + 2], gh2);
      gh0 = MFMA16(ahh, WHH_L[kt * 3 + 0], gh0);
      gh1 = MFMA16(ahh, WHH_L[kt * 3 + 1], gh1);
      gh2 = MFMA16(ahh, WHH_L[kt * 3 + 2], gh2);
    }

    // ---- reduce 4 wave-partials (C/D layout: row=quad*4+q, col=l15)
#pragma unroll
    for (int q = 0; q < 4; ++q) {
      const int base = (quad * 4 + q) * 16 + l15;
      red[wave][0][base] = gi0[q]; red[wave][1][base] = gi1[q]; red[wave][2][base] = gi2[q];
      red[wave][3][base] = gh0[q]; red[wave][4][base] = gh1[q]; red[wave][5][base] = gh2[q];
    }
    __syncthreads();
    float sR = 0, sZ = 0, sN = 0, hR = 0, hZ = 0, hN = 0;
#pragma unroll
    for (int w = 0; w < 4; ++w) {
      sR += red[w][0][tid]; sZ += red[w][1][tid]; sN += red[w][2][tid];
      hR += red[w][3][tid]; hZ += red[w][4][tid]; hN += red[w][5][tid];
    }
    const float rr = sigmoidf_(sR + bieR + hR + bheR);
    const float zz = sigmoidf_(sZ + bieZ + hZ + bheZ);
    const float nn = tanhf_(sN + bieN + rr * (hN + bheN));
    h_reg = (1.0f - zz) * nn + zz * h_reg;
    unsigned short ph, pl;
    split_bf(h_reg, ph, pl);
    // fire-and-forget stamped store — no drain, no flag
    store_u32_mall(HbP + (size_t)wslot * 65536 + (size_t)onrow * 512 + ig,
                   (unsigned int)ph | ((((unsigned int)pl & 0xFFFEu) | wstamp) << 16));
    __syncthreads();  // LDS red[] WAR protection (drains the store too)
  }

  // ===================== decoder weights (fp32 -> split, reuse regs) ========
  bf16x8 D1H[12], D1L[12], D2H[12], D2L[12], DHH[12], DHL[12];
#pragma unroll
  for (int kt = 0; kt < 4; ++kt)
#pragma unroll
    for (int nt = 0; nt < 3; ++nt) {
      const size_t row = (size_t)(nt * 512 + ib + l15);
      const int    k   = (wave * 4 + kt) * 32 + quad * 8;
      split8(WihD + row * 1024 + k,       D1H[kt * 3 + nt], D1L[kt * 3 + nt]);
      split8(WihD + row * 1024 + 512 + k, D2H[kt * 3 + nt], D2L[kt * 3 + nt]);
      split8(WhhD + row * 512 + k,        DHH[kt * 3 + nt], DHL[kt * 3 + nt]);
    }

  float* orow = out + (size_t)ob * 49152 + (size_t)ig * 96 + od;

  // ===================== decoder: 48 steps (global step gt = 256 + t) =======
  for (int t = 0; t < 48; ++t) {
    const int gt    = 256 + t;
    const int rslot = gt & 1;
    const int wslot = (gt + 1) & 1;
    const unsigned int rstamp = ((unsigned int)(gt + 1) >> 1) & 1u;
    const unsigned int wstamp = ((unsigned int)(gt + 2) >> 1) & 1u;

    // ---- x1 part of gi (independent of h)
    f32x4 gi0 = {0,0,0,0}, gi1 = {0,0,0,0}, gi2 = {0,0,0,0};
    const size_t x1b = ((size_t)t * 128 + an) * 512 + quad * 8;  // staged
    const int    tau = 2 * t + ad;                                // direct
#pragma unroll
    for (int kt = 0; kt < 4; ++kt) {
      bf16x8 axh, axl;
      if constexpr (STAGED) {
        axh = *reinterpret_cast<const bf16x8*>(XX1H + x1b + (wave * 4 + kt) * 32);
        axl = *reinterpret_cast<const bf16x8*>(XX1L + x1b + (wave * 4 + kt) * 32);
      } else {
        float xv[8];
#pragma unroll
        for (int j = 0; j < 8; ++j)
          xv[j] = X1[(size_t)ab * 49152 +
                     (size_t)((wave * 4 + kt) * 32 + quad * 8 + j) * 96 + tau];
        split8a(xv, axh, axl);
      }
      gi0 = MFMA16(axh, D2H[kt * 3 + 0], gi0);
      gi1 = MFMA16(axh, D2H[kt * 3 + 1], gi1);
      gi2 = MFMA16(axh, D2H[kt * 3 + 2], gi2);
      gi0 = MFMA16(axl, D2H[kt * 3 + 0], gi0);
      gi1 = MFMA16(axl, D2H[kt * 3 + 1], gi1);
      gi2 = MFMA16(axl, D2H[kt * 3 + 2], gi2);
      gi0 = MFMA16(axh, D2L[kt * 3 + 0], gi0);
      gi1 = MFMA16(axh, D2L[kt * 3 + 1], gi1);
      gi2 = MFMA16(axh, D2L[kt * 3 + 2], gi2);
    }

    // ---- stamped h read
    const unsigned int* hrow = HbP + (size_t)rslot * 65536 + (size_t)an * 512 + quad * 8;
    u32x4 hv[4][2];
    load_h8_stamped(hrow + (size_t)wave * 128, hv, rstamp);

    // ---- h parts: gi += h@Wd1^T (din == h), gh = h@WhhD^T
    f32x4 gh0 = {0,0,0,0}, gh1 = {0,0,0,0}, gh2 = {0,0,0,0};
#pragma unroll
    for (int kt = 0; kt < 4; ++kt) {
      bf16x8 ahh, ahl;
      union { unsigned short u; __bf16 b; } c;
#pragma unroll
      for (int j = 0; j < 8; ++j) {
        const unsigned int w = hv[kt][j >> 2][j & 3];
        c.u = (unsigned short)(w & 0xffffu); ahh[j] = c.b;
        c.u = (unsigned short)(w >> 16);     ahl[j] = c.b;
      }
      gi0 = MFMA16(ahh, D1H[kt * 3 + 0], gi0);
      gi1 = MFMA16(ahh, D1H[kt * 3 + 1], gi1);
      gi2 = MFMA16(ahh, D1H[kt * 3 + 2], gi2);
      gi0 = MFMA16(ahl, D1H[kt * 3 + 0], gi0);
      gi1 = MFMA16(ahl, D1H[kt * 3 + 1], gi1);
      gi2 = MFMA16(ahl, D1H[kt * 3 + 2], gi2);
      gi0 = MFMA16(ahh, D1L[kt * 3 + 0], gi0);
      gi1 = MFMA16(ahh, D1L[kt * 3 + 1], gi1);
      gi2 = MFMA16(ahh, D1L[kt * 3 + 2], gi2);
      gh0 = MFMA16(ahh, DHH[kt * 3 + 0], gh0);
      gh1 = MFMA16(ahh, DHH[kt * 3 + 1], gh1);
      gh2 = MFMA16(ahh, DHH[kt * 3 + 2], gh2);
      gh0 = MFMA16(ahl, DHH[kt * 3 + 0], gh0);
      gh1 = MFMA16(ahl, DHH[kt * 3 + 1], gh1);
      gh2 = MFMA16(ahl, DHH[kt * 3 + 2], gh2);
      gh0 = MFMA16(ahh, DHL[kt * 3 + 0], gh0);
      gh1 = MFMA16(ahh, DHL[kt * 3 + 1], gh1);
      gh2 = MFMA16(ahh, DHL[kt * 3 + 2], gh2);
    }

#pragma unroll
    for (int q = 0; q < 4; ++q) {
      const int base = (quad * 4 + q) * 16 + l15;
      red[wave][0][base] = gi0[q]; red[wave][1][base] = gi1[q]; red[wave][2][base] = gi2[q];
      red[wave][3][base] = gh0[q]; red[wave][4][base] = gh1[q]; red[wave][5][base] = gh2[q];
    }
    __syncthreads();
    float sR = 0, sZ = 0, sN = 0, hR = 0, hZ = 0, hN = 0;
#pragma unroll
    for (int w = 0; w < 4; ++w) {
      sR += red[w][0][tid]; sZ += red[w][1][tid]; sN += red[w][2][tid];
      hR += red[w][3][tid]; hZ += red[w][4][tid]; hN += red[w][5][tid];
    }
    const float rr = sigmoidf_(sR + bidR + hR + bhdR);
    const float zz = sigmoidf_(sZ + bidZ + hZ + bhdZ);
    const float nn = tanhf_(sN + bidN + rr * (hN + bhdN));
    h_reg = (1.0f - zz) * nn + zz * h_reg;
    unsigned short ph, pl;
    split_bf(h_reg, ph, pl);
    store_u32_mall(HbP + (size_t)wslot * 65536 + (size_t)onrow * 512 + ig,
                   (unsigned int)ph | ((((unsigned int)pl & 0xFFFEu) | wstamp) << 16));
    orow[2 * t] = h_reg;  // o[b][ig][2t+d]
    __syncthreads();      // LDS red[] WAR protection (drains the store too)
  }
}

extern "C" void kernel_launch(void* const* d_in, const int* in_sizes, int n_in,
                              void* d_out, int out_size, void* d_ws, size_t ws_size,
                              hipStream_t stream) {
  (void)in_sizes; (void)n_in; (void)out_size;
  const float* X0   = (const float*)d_in[0];
  const float* X1   = (const float*)d_in[1];
  // d_in[2] = seqlen (unused, fixed 512)
  const float* WihE = (const float*)d_in[3];
  const float* WhhE = (const float*)d_in[4];
  const float* bihE = (const float*)d_in[5];
  const float* bhhE = (const float*)d_in[6];
  const float* WihD = (const float*)d_in[7];
  const float* WhhD = (const float*)d_in[8];
  const float* bihD = (const float*)d_in[9];
  const float* bhhD = (const float*)d_in[10];
  unsigned char* ws = (unsigned char*)d_ws;

  const bool staged = (ws_size >= NEED_FULL);  // ws_size constant -> graph-safe

  // Zero the h ring: stamp-0 zeros ARE the valid h(0) (runtime's inter-kernel
  // release makes the memset visible to the persistent kernel's MALL reads —
  // same mechanism the r10 flag memset relied on, HW-proven).
  hipMemsetAsync(ws + OFF_HB, 0, 524288, stream);
  if (staged) {
    prep_x0<<<dim3(64, 32), 256, 0, stream>>>(X0, (unsigned short*)(ws + OFF_XX0H));
    prep_x1<<<dim3(64, 16), 256, 0, stream>>>(X1, (unsigned short*)(ws + OFF_XX1H));
    rnn_persistent<true><<<256, 256, 0, stream>>>(ws, X0, X1, WihE, WhhE, bihE, bhhE,
                                                  WihD, WhhD, bihD, bhhD, (float*)d_out);
  } else {
    rnn_persistent<false><<<256, 256, 0, stream>>>(ws, X0, X1, WihE, WhhE, bihE, bhhE,
                                                   WihD, WhhD, bihD, bhhD, (float*)d_out);
  }
}